// Round 18
// baseline (102.318 us; speedup 1.0000x reference)
//
#include <hip/hip_runtime.h>
#include <hip/hip_bf16.h>
#include <hip/hip_fp16.h>
#include <math.h>

#define BATCH 4
#define CH    256
#define NPOS  4096
#define DQK   32
#define LOG2E 1.4426950408889634f
#define QB2   (-43.280851226668903f)   // -30*log2(e): exp2(S*log2e + QB2) = exp(S-30)

typedef __attribute__((ext_vector_type(8))) short bf16x8;
typedef __attribute__((ext_vector_type(4))) float f32x4;
typedef __attribute__((ext_vector_type(4))) _Float16 f16x4;

static __device__ __forceinline__ unsigned int pack_bf2(float a, float b) {
    __hip_bfloat162 h = __float22bfloat162_rn(make_float2(a, b));
    return *reinterpret_cast<unsigned int*>(&h);
}
static __device__ __forceinline__ unsigned short f2bf1(float f) {
    unsigned int u = __float_as_uint(f);
    u += 0x7fff + ((u >> 16) & 1);
    return (unsigned short)(u >> 16);
}

// ---------------- Kernel 0: W -> bf16 (Wq, bq pre-scaled by log2e) ----------------
__global__ __launch_bounds__(256) void conv_w(
    const float* __restrict__ Wq, const float* __restrict__ bq,
    const float* __restrict__ Wk, const float* __restrict__ bk,
    const float* __restrict__ Wv, const float* __restrict__ bv,
    __hip_bfloat16* __restrict__ Wbf, float* __restrict__ bcat)
{
    const int co = blockIdx.x;    // 0..319
    const int ci = threadIdx.x;   // 0..255
    const float* src; float scale = 1.f;
    if (co < 32)      { src = Wq + (size_t)co * 256;        scale = LOG2E; }
    else if (co < 64) { src = Wk + (size_t)(co - 32) * 256; }
    else              { src = Wv + (size_t)(co - 64) * 256; }
    *reinterpret_cast<unsigned short*>(Wbf + (size_t)co * 256 + ci) =
        f2bf1(src[ci] * scale);
    if (ci == 0)
        bcat[co] = co < 32 ? bq[co] * LOG2E
                 : (co < 64 ? bk[co - 32] : bv[co - 64]);
}

// ---------------- Kernel 1: MFMA projection GEMM (q,k bf16; v f16 blocked) ----------------
__global__ __launch_bounds__(256) void qkv_proj_mfma(
    const float* __restrict__ x,
    const __hip_bfloat16* __restrict__ Wbf, const float* __restrict__ bcat,
    __hip_bfloat16* __restrict__ qb, __hip_bfloat16* __restrict__ kb,
    unsigned short* __restrict__ vb)
{
    __shared__ alignas(16) unsigned char Xl[16384];
    const int tid  = threadIdx.x;
    const int wave = tid >> 6, lane = tid & 63;
    const int g    = lane >> 4, lm = lane & 15;
    const int n0   = blockIdx.x * 32;
    const int b    = blockIdx.y;

    {
        const int c   = tid;
        const int ktc = c >> 5, gc = (c >> 3) & 3, jc = c & 7;
        const unsigned xw = (unsigned)(4 * ktc + gc);
        const float* xp = x + ((size_t)b * CH + c) * NPOS + n0;
        #pragma unroll
        for (int i = 0; i < 8; ++i) {
            const float4 v4 = reinterpret_cast<const float4*>(xp)[i];
            const float vv[4] = {v4.x, v4.y, v4.z, v4.w};
            #pragma unroll
            for (int e = 0; e < 4; ++e) {
                const int nrel = 4 * i + e;
                const unsigned off =
                    (unsigned)(((nrel >> 4) * 8 + ktc) * 1024)
                  + ((((unsigned)(gc * 16 + (nrel & 15))) ^ xw) * 16)
                  + (unsigned)(jc * 2);
                *reinterpret_cast<unsigned short*>(Xl + off) = f2bf1(vv[e]);
            }
        }
    }
    __syncthreads();

    bf16x8 xf[2][8];
    #pragma unroll
    for (int nt = 0; nt < 2; ++nt)
        #pragma unroll
        for (int kt = 0; kt < 8; ++kt) {
            const unsigned slot = (unsigned)lane ^ (unsigned)(4 * kt + g);
            xf[nt][kt] = *reinterpret_cast<const bf16x8*>(
                Xl + (unsigned)((nt * 8 + kt) * 1024) + slot * 16);
        }

    #pragma unroll
    for (int s = 0; s < 5; ++s) {
        const int cot = wave * 5 + s;
        const int cog = cot * 16;

        bf16x8 wf[8];
        const __hip_bfloat16* wrow = Wbf + (size_t)(cog + lm) * 256;
        #pragma unroll
        for (int kt = 0; kt < 8; ++kt)
            wf[kt] = *reinterpret_cast<const bf16x8*>(wrow + 32 * kt + 8 * g);

        const float4 b4 = *reinterpret_cast<const float4*>(bcat + cog + 4 * g);
        f32x4 a0 = {b4.x, b4.y, b4.z, b4.w};
        f32x4 a1 = a0;
        #pragma unroll
        for (int kt = 0; kt < 8; ++kt) {
            a0 = __builtin_amdgcn_mfma_f32_16x16x32_bf16(wf[kt], xf[0][kt], a0, 0, 0, 0);
            a1 = __builtin_amdgcn_mfma_f32_16x16x32_bf16(wf[kt], xf[1][kt], a1, 0, 0, 0);
        }

        if (cot < 4) {
            __hip_bfloat16* dst = (cot < 2 ? qb : kb);
            const int cb = (cot < 2 ? cot * 16 : cot * 16 - 32);
            #pragma unroll
            for (int nt = 0; nt < 2; ++nt) {
                f32x4 a = nt ? a1 : a0;
                int n = n0 + 16 * nt + lm;
                uint2 w;
                w.x = pack_bf2(a[0], a[1]);
                w.y = pack_bf2(a[2], a[3]);
                *(uint2*)(dst + ((size_t)b * NPOS + n) * DQK + cb + 4 * g) = w;
            }
        } else {
            const int cbase = cot * 16 - 64;
            #pragma unroll
            for (int nt = 0; nt < 2; ++nt) {
                f32x4 a = nt ? a1 : a0;
                int n = n0 + 16 * nt + lm;
                int n64 = n >> 6, half = (n >> 5) & 1, nin = n & 31;
                #pragma unroll
                for (int r = 0; r < 4; ++r) {
                    int c = cbase + 4 * g + r;
                    size_t off = (((size_t)b * 16 + (c >> 4)) * 64 + n64) * 1024
                               + (size_t)half * 512 + (c & 15) * 32 + nin;
                    _Float16 hv = (_Float16)a[r];
                    vb[off] = *reinterpret_cast<unsigned short*>(&hv);
                }
            }
        }
    }
}

// ---------------- Kernel 2: register-P flash attention (no LDS, no barriers in loop) ----------------
// grid 256 (b=bid&3, 64 m-rows/block), 8 waves = (kt 0..3) x (chalf 0..1).
// Wave: keys [16kt,16kt+16) of each 64-tile, channels [128*chalf,+128), ALL 64 m.
// QK: S^T = mfma16x16x32(K,Q) -> exp2 -> f16 P stays IN REGISTERS (output layout
// == B-operand layout of 16x16x16 MFMA). PV: acc[8][4] += mfma16x16x16f16(V,P).
// One-time chunked LDS merge over kt at the end.
__global__ __launch_bounds__(512, 2) void flash_pam_kernel(
    const __hip_bfloat16* __restrict__ qb, const __hip_bfloat16* __restrict__ kb,
    const unsigned short* __restrict__ vb, const float* __restrict__ x,
    const float* __restrict__ gamma, float* __restrict__ out)
{
    __shared__ float mbuf[2][4][64][20];   // 40KB merge buffer (stride 20 = pad)
    __shared__ float lred[4][4][16];       // [kt][mt][lm]
    __shared__ float linvA[64];

    const int tid  = threadIdx.x;
    const int wave = tid >> 6;
    const int lane = tid & 63;
    const int g    = lane >> 4;
    const int lm   = lane & 15;
    const int bid  = blockIdx.x;
    const int b    = bid & 3;
    const int m0   = (bid >> 2) * 64;
    const int kt   = wave & 3;
    const int chalf= wave >> 2;

    // Q B-fragments for all 4 m-tiles
    bf16x8 qf[4];
    #pragma unroll
    for (int mt = 0; mt < 4; ++mt)
        qf[mt] = *reinterpret_cast<const bf16x8*>(
            qb + ((size_t)b * NPOS + m0 + 16 * mt + lm) * DQK + 8 * g);

    // K rows 16kt+lm (A-operand), V fragment base (A-operand of 16x16x16)
    const __hip_bfloat16* kgl =
        kb + (size_t)b * NPOS * DQK + (16 * kt + lm) * DQK + 8 * g;
    const unsigned short* vgl = vb + (size_t)b * 16 * 65536
        + (size_t)(8 * chalf) * 65536
        + (kt >> 1) * 512 + lm * 32 + (kt & 1) * 16 + 4 * g;

    f32x4 acc[8][4];
    #pragma unroll
    for (int ct = 0; ct < 8; ++ct)
        #pragma unroll
        for (int mt = 0; mt < 4; ++mt) acc[ct][mt] = (f32x4){0.f, 0.f, 0.f, 0.f};
    float ls[4] = {0.f, 0.f, 0.f, 0.f};

    for (int t = 0; t < 64; ++t) {
        const bf16x8 kf = *reinterpret_cast<const bf16x8*>(kgl + (size_t)t * 2048);
        f16x4 vf[8];
        #pragma unroll
        for (int ct = 0; ct < 8; ++ct)
            vf[ct] = *reinterpret_cast<const f16x4*>(
                vgl + (size_t)ct * 65536 + (size_t)t * 1024);

        f16x4 pf[4];
        #pragma unroll
        for (int mt = 0; mt < 4; ++mt) {
            f32x4 zb = {QB2, QB2, QB2, QB2};
            f32x4 s = __builtin_amdgcn_mfma_f32_16x16x32_bf16(kf, qf[mt], zb, 0, 0, 0);
            float p0 = exp2f(s[0]), p1 = exp2f(s[1]);
            float p2 = exp2f(s[2]), p3 = exp2f(s[3]);
            ls[mt] += (p0 + p1) + (p2 + p3);
            f16x4 pv;
            pv[0] = (_Float16)p0; pv[1] = (_Float16)p1;
            pv[2] = (_Float16)p2; pv[3] = (_Float16)p3;
            pf[mt] = pv;
        }

        __builtin_amdgcn_s_setprio(1);
        #pragma unroll
        for (int ct = 0; ct < 8; ++ct)
            #pragma unroll
            for (int mt = 0; mt < 4; ++mt)
                acc[ct][mt] = __builtin_amdgcn_mfma_f32_16x16x16f16(
                    vf[ct], pf[mt], acc[ct][mt], 0, 0, 0);
        __builtin_amdgcn_s_setprio(0);
    }

    // l partials: reduce over g, publish per (kt, mt, m); chalf=0 only (dup)
    #pragma unroll
    for (int mt = 0; mt < 4; ++mt) {
        float v = ls[mt];
        v += __shfl_xor(v, 16);
        v += __shfl_xor(v, 32);
        if (chalf == 0 && lane < 16) lred[kt][mt][lane] = v;
    }
    __syncthreads();
    if (tid < 64) {
        const int mt = tid >> 4, l = tid & 15;
        linvA[tid] = 1.f / (lred[0][mt][l] + lred[1][mt][l]
                          + lred[2][mt][l] + lred[3][mt][l]);
    }
    __syncthreads();

    // merge over kt + cooperative epilogue, one ct-chunk at a time
    const float gmv = gamma[0];
    #pragma unroll
    for (int ct = 0; ct < 8; ++ct) {
        float* wp = &mbuf[chalf][kt][lane][0];
        #pragma unroll
        for (int mt = 0; mt < 4; ++mt)
            *reinterpret_cast<f32x4*>(wp + 4 * mt) = acc[ct][mt];
        __syncthreads();

        #pragma unroll
        for (int s = 0; s < 4; ++s) {
            const int slot  = s * 512 + tid;        // 0..2047
            const int m_loc = slot & 63;
            const int c_sel = slot >> 6;            // 0..31
            const int ch2   = c_sel >> 4;
            const int ch_in = c_sel & 15;
            const int ln    = ((ch_in >> 2) << 4) | (m_loc & 15);
            const int idx   = ((m_loc >> 4) << 2) | (ch_in & 3);
            const float v = mbuf[ch2][0][ln][idx] + mbuf[ch2][1][ln][idx]
                          + mbuf[ch2][2][ln][idx] + mbuf[ch2][3][ln][idx];
            const int c = 128 * ch2 + 16 * ct + ch_in;
            const size_t oidx = ((size_t)b * CH + c) * NPOS + m0 + m_loc;
            out[oidx] = gmv * v * linvA[m_loc] + x[oidx];
        }
        __syncthreads();
    }
}

extern "C" void kernel_launch(void* const* d_in, const int* in_sizes, int n_in,
                              void* d_out, int out_size, void* d_ws, size_t ws_size,
                              hipStream_t stream) {
    const float* x  = (const float*)d_in[0];
    const float* Wq = (const float*)d_in[1];
    const float* bq = (const float*)d_in[2];
    const float* Wk = (const float*)d_in[3];
    const float* bk = (const float*)d_in[4];
    const float* Wv = (const float*)d_in[5];
    const float* bv = (const float*)d_in[6];
    const float* gm = (const float*)d_in[7];
    float* out = (float*)d_out;

    __hip_bfloat16* qbuf = (__hip_bfloat16*)d_ws;
    __hip_bfloat16* kbuf = qbuf + (size_t)BATCH * NPOS * DQK;      // +1MB
    unsigned short* vbuf = (unsigned short*)(kbuf + (size_t)BATCH * NPOS * DQK); // +1MB
    __hip_bfloat16* wbf  = (__hip_bfloat16*)(vbuf + (size_t)BATCH * CH * NPOS);  // +8MB
    float* bcat = (float*)(wbf + 320 * 256);                       // +160KB

    conv_w<<<dim3(320), 256, 0, stream>>>(Wq, bq, Wk, bk, Wv, bv, wbf, bcat);
    qkv_proj_mfma<<<dim3(NPOS / 32, BATCH), 256, 0, stream>>>(
        x, wbf, bcat, qbuf, kbuf, vbuf);
    flash_pam_kernel<<<dim3(NPOS / 64 * BATCH), 512, 0, stream>>>(
        qbuf, kbuf, vbuf, x, gm, out);
}

// Round 19
// 72.874 us; speedup vs baseline: 1.4041x; 1.4041x over previous
//
#include <hip/hip_runtime.h>
#include <hip/hip_bf16.h>
#include <math.h>

#define BATCH 4
#define CH    256
#define NPOS  4096
#define DQK   32
#define LOG2E 1.4426950408889634f
#define QB2   (-28.853900817779268f)   // -20*log2(e): exp2(S*log2e + QB2) = exp(S-20)

typedef __attribute__((ext_vector_type(8))) short bf16x8;
typedef __attribute__((ext_vector_type(4))) float f32x4;

static __device__ __forceinline__ unsigned int pack_bf2(float a, float b) {
    __hip_bfloat162 h = __float22bfloat162_rn(make_float2(a, b));
    return *reinterpret_cast<unsigned int*>(&h);
}
static __device__ __forceinline__ unsigned short f2bf1(float f) {
    unsigned int u = __float_as_uint(f);
    u += 0x7fff + ((u >> 16) & 1);
    return (unsigned short)(u >> 16);
}

// Barrier WITHOUT the vmcnt(0) drain.
static __device__ __forceinline__ void lds_barrier() {
    asm volatile("s_waitcnt lgkmcnt(0)" ::: "memory");
    __builtin_amdgcn_s_barrier();
    asm volatile("" ::: "memory");
}

// ---------------- Kernel 0: W -> bf16 (Wq, bq pre-scaled by log2e) ----------------
__global__ __launch_bounds__(256) void conv_w(
    const float* __restrict__ Wq, const float* __restrict__ bq,
    const float* __restrict__ Wk, const float* __restrict__ bk,
    const float* __restrict__ Wv, const float* __restrict__ bv,
    __hip_bfloat16* __restrict__ Wbf, float* __restrict__ bcat)
{
    const int co = blockIdx.x;    // 0..319
    const int ci = threadIdx.x;   // 0..255
    const float* src; float scale = 1.f;
    if (co < 32)      { src = Wq + (size_t)co * 256;        scale = LOG2E; }
    else if (co < 64) { src = Wk + (size_t)(co - 32) * 256; }
    else              { src = Wv + (size_t)(co - 64) * 256; }
    *reinterpret_cast<unsigned short*>(Wbf + (size_t)co * 256 + ci) =
        f2bf1(src[ci] * scale);
    if (ci == 0)
        bcat[co] = co < 32 ? bq[co] * LOG2E
                 : (co < 64 ? bk[co - 32] : bv[co - 64]);
}

// ---------------- Kernel 1: MFMA projection GEMM, x staged once via LDS ----------------
__global__ __launch_bounds__(256) void qkv_proj_mfma(
    const float* __restrict__ x,
    const __hip_bfloat16* __restrict__ Wbf, const float* __restrict__ bcat,
    __hip_bfloat16* __restrict__ qb, __hip_bfloat16* __restrict__ kb,
    __hip_bfloat16* __restrict__ vb)
{
    __shared__ alignas(16) unsigned char Xl[16384];
    const int tid  = threadIdx.x;
    const int wave = tid >> 6, lane = tid & 63;
    const int g    = lane >> 4, lm = lane & 15;
    const int n0   = blockIdx.x * 32;
    const int b    = blockIdx.y;

    {
        const int c   = tid;
        const int ktc = c >> 5, gc = (c >> 3) & 3, jc = c & 7;
        const unsigned xw = (unsigned)(4 * ktc + gc);
        const float* xp = x + ((size_t)b * CH + c) * NPOS + n0;
        #pragma unroll
        for (int i = 0; i < 8; ++i) {
            const float4 v4 = reinterpret_cast<const float4*>(xp)[i];
            const float vv[4] = {v4.x, v4.y, v4.z, v4.w};
            #pragma unroll
            for (int e = 0; e < 4; ++e) {
                const int nrel = 4 * i + e;
                const unsigned off =
                    (unsigned)(((nrel >> 4) * 8 + ktc) * 1024)
                  + ((((unsigned)(gc * 16 + (nrel & 15))) ^ xw) * 16)
                  + (unsigned)(jc * 2);
                *reinterpret_cast<unsigned short*>(Xl + off) = f2bf1(vv[e]);
            }
        }
    }
    __syncthreads();

    bf16x8 xf[2][8];
    #pragma unroll
    for (int nt = 0; nt < 2; ++nt)
        #pragma unroll
        for (int kt = 0; kt < 8; ++kt) {
            const unsigned slot = (unsigned)lane ^ (unsigned)(4 * kt + g);
            xf[nt][kt] = *reinterpret_cast<const bf16x8*>(
                Xl + (unsigned)((nt * 8 + kt) * 1024) + slot * 16);
        }

    #pragma unroll
    for (int s = 0; s < 5; ++s) {
        const int cot = wave * 5 + s;
        const int cog = cot * 16;

        bf16x8 wf[8];
        const __hip_bfloat16* wrow = Wbf + (size_t)(cog + lm) * 256;
        #pragma unroll
        for (int kt = 0; kt < 8; ++kt)
            wf[kt] = *reinterpret_cast<const bf16x8*>(wrow + 32 * kt + 8 * g);

        const float4 b4 = *reinterpret_cast<const float4*>(bcat + cog + 4 * g);
        f32x4 a0 = {b4.x, b4.y, b4.z, b4.w};
        f32x4 a1 = a0;
        #pragma unroll
        for (int kt = 0; kt < 8; ++kt) {
            a0 = __builtin_amdgcn_mfma_f32_16x16x32_bf16(wf[kt], xf[0][kt], a0, 0, 0, 0);
            a1 = __builtin_amdgcn_mfma_f32_16x16x32_bf16(wf[kt], xf[1][kt], a1, 0, 0, 0);
        }

        if (cot < 4) {
            __hip_bfloat16* dst = (cot < 2 ? qb : kb);
            const int cb = (cot < 2 ? cot * 16 : cot * 16 - 32);
            #pragma unroll
            for (int nt = 0; nt < 2; ++nt) {
                f32x4 a = nt ? a1 : a0;
                int n = n0 + 16 * nt + lm;
                uint2 w;
                w.x = pack_bf2(a[0], a[1]);
                w.y = pack_bf2(a[2], a[3]);
                *(uint2*)(dst + ((size_t)b * NPOS + n) * DQK + cb + 4 * g) = w;
            }
        } else {
            const int cbase = cot * 16 - 64;
            #pragma unroll
            for (int nt = 0; nt < 2; ++nt) {
                f32x4 a = nt ? a1 : a0;
                int n = n0 + 16 * nt + lm;
                int n64 = n >> 6, half = (n >> 5) & 1, nin = n & 31;
                #pragma unroll
                for (int r = 0; r < 4; ++r) {
                    int c = cbase + 4 * g + r;
                    size_t off = (((size_t)b * 16 + (c >> 4)) * 64 + n64) * 1024
                               + (size_t)half * 512 + (c & 15) * 32 + nin;
                    *reinterpret_cast<unsigned short*>(vb + off) = f2bf1(a[r]);
                }
            }
        }
    }
}

// ---------------- Kernel 2: cooperative MFMA flash — exact R8 structure ----------------
// grid 256: b = bid&3 (one batch per XCD pair), 64 m-rows/block. 8 waves.
// Per key-tile t: QK wave-split (2/16 S^T subtiles) -> exp2 -> P LDS;
// PV: wave owns 32 channels x all 64 m. Double-buffered P, one lgkm-only
// barrier per tile; V(t+1)/K(t+2) prefetched in plain C++ (compiler-scheduled).
__global__ __launch_bounds__(512) void flash_pam_kernel(
    const __hip_bfloat16* __restrict__ qb, const __hip_bfloat16* __restrict__ kb,
    const __hip_bfloat16* __restrict__ vb, const float* __restrict__ x,
    const float* __restrict__ gamma, float* __restrict__ out)
{
    __shared__ alignas(16) unsigned char Pl[2][8192];
    __shared__ float lred[4][4][16];   // [kt][mt][lm]

    const int tid  = threadIdx.x;
    const int wave = tid >> 6;
    const int lane = tid & 63;
    const int g    = lane >> 4;
    const int lm   = lane & 15;
    const int bid  = blockIdx.x;
    const int b    = bid & 3;
    const int m0   = (bid >> 2) * 64;
    const int kt   = wave & 3;
    const int mtA  = (wave >> 2) * 2;
    const unsigned swz = (unsigned)(lm & 7) << 4;

    const bf16x8 qfA = *reinterpret_cast<const bf16x8*>(
        qb + ((size_t)b * NPOS + m0 + 16 * mtA + lm) * DQK + 8 * g);
    const bf16x8 qfB = *reinterpret_cast<const bf16x8*>(
        qb + ((size_t)b * NPOS + m0 + 16 * mtA + 16 + lm) * DQK + 8 * g);

    const __hip_bfloat16* kbb = kb + (size_t)b * NPOS * DQK;
    const int koff0 = (16 * kt + lm) * DQK + 8 * g;           // + t*2048
    const __hip_bfloat16* vbb = vb + (size_t)b * 16 * 64 * 1024;
    int vfb[4];                                                // + t*1024
    #pragma unroll
    for (int cti = 0; cti < 2; ++cti)
        #pragma unroll
        for (int kc = 0; kc < 2; ++kc)
            vfb[2 * cti + kc] = (2 * wave + cti) * 65536 + kc * 512 + lm * 32 + 8 * g;

    const unsigned wbA = (unsigned)(16 * mtA + lm) * 128
                       + (((unsigned)(32 * kt + 8 * g)) ^ swz);
    const unsigned wbB = wbA + 16 * 128;

    unsigned char* P0 = &Pl[0][0];
    unsigned char* P1 = &Pl[1][0];

    f32x4 acc[2][4];
    #pragma unroll
    for (int i = 0; i < 2; ++i)
        #pragma unroll
        for (int j = 0; j < 4; ++j) acc[i][j] = (f32x4){0.f, 0.f, 0.f, 0.f};
    float lsA = 0.f, lsB = 0.f;

#define LOADK(dst, tk_) \
    dst = *reinterpret_cast<const bf16x8*>(kbb + koff0 + (tk_) * 2048);

#define LOADV(dst, tv_) { \
    _Pragma("unroll") for (int f = 0; f < 4; ++f) \
        dst[f] = *reinterpret_cast<const bf16x8*>(vbb + vfb[f] + (tv_) * 1024); }

#define QKW(KU, PW) { \
    f32x4 zb = {QB2, QB2, QB2, QB2}; \
    f32x4 sA = __builtin_amdgcn_mfma_f32_16x16x32_bf16(KU, qfA, zb, 0, 0, 0); \
    f32x4 sB = __builtin_amdgcn_mfma_f32_16x16x32_bf16(KU, qfB, zb, 0, 0, 0); \
    { float p0 = exp2f(sA[0]), p1 = exp2f(sA[1]); \
      float p2 = exp2f(sA[2]), p3 = exp2f(sA[3]); \
      lsA += (p0 + p1) + (p2 + p3); \
      uint2 w; w.x = pack_bf2(p0, p1); w.y = pack_bf2(p2, p3); \
      *reinterpret_cast<uint2*>((PW) + wbA) = w; } \
    { float p0 = exp2f(sB[0]), p1 = exp2f(sB[1]); \
      float p2 = exp2f(sB[2]), p3 = exp2f(sB[3]); \
      lsB += (p0 + p1) + (p2 + p3); \
      uint2 w; w.x = pack_bf2(p0, p1); w.y = pack_bf2(p2, p3); \
      *reinterpret_cast<uint2*>((PW) + wbB) = w; } }

#define PVt(PR, VR) { \
    _Pragma("unroll") for (int kc = 0; kc < 2; ++kc) { \
        bf16x8 pf[4]; \
        _Pragma("unroll") for (int mt = 0; mt < 4; ++mt) \
            pf[mt] = *reinterpret_cast<const bf16x8*>( \
                (PR) + (unsigned)(16 * mt + lm) * 128 \
                     + (((unsigned)(kc * 64 + 16 * g)) ^ swz)); \
        __builtin_amdgcn_s_setprio(1); \
        _Pragma("unroll") for (int cti = 0; cti < 2; ++cti) \
            _Pragma("unroll") for (int mt = 0; mt < 4; ++mt) \
                acc[cti][mt] = __builtin_amdgcn_mfma_f32_16x16x32_bf16( \
                    VR[2 * cti + kc], pf[mt], acc[cti][mt], 0, 0, 0); \
        __builtin_amdgcn_s_setprio(0); } }

// BODY(t): prefetch V(t+1)/K(t+2); QK(t+1)->PW; PV(t) from PR+VR; lgkm barrier.
#define BODY(t_, PR, PW, VR, VL, KU, KL) { \
    { int tv = (t_) + 1; if (tv > 63) tv = 63; LOADV(VL, tv); } \
    { int tk2 = (t_) + 2; if (tk2 > 63) tk2 = 63; LOADK(KL, tk2); } \
    QKW(KU, PW); \
    PVt(PR, VR); \
    lds_barrier(); }

    // prologue
    bf16x8 kA, kB, vA[4], vB[4];
    LOADK(kA, 0);
    LOADV(vA, 0);
    LOADK(kB, 1);
    QKW(kA, P0);
    lds_barrier();

    for (int it = 0; it < 31; ++it) {
        BODY(2 * it,     P0, P1, vA, vB, kB, kA);
        BODY(2 * it + 1, P1, P0, vB, vA, kA, kB);
    }
    BODY(62, P0, P1, vA, vB, kB, kA);
    PVt(P1, vB);   // t = 63

    // merge per-subtile l partials
    lsA += __shfl_xor(lsA, 16); lsA += __shfl_xor(lsA, 32);
    lsB += __shfl_xor(lsB, 16); lsB += __shfl_xor(lsB, 32);
    if (lane < 16) {
        lred[kt][mtA][lm]     = lsA;
        lred[kt][mtA + 1][lm] = lsB;
    }
    __syncthreads();

    float linv[4];
    #pragma unroll
    for (int mt = 0; mt < 4; ++mt)
        linv[mt] = 1.f / (lred[0][mt][lm] + lred[1][mt][lm]
                        + lred[2][mt][lm] + lred[3][mt][lm]);

    const float gmv = gamma[0];
    #pragma unroll
    for (int cti = 0; cti < 2; ++cti)
        #pragma unroll
        for (int mt = 0; mt < 4; ++mt)
            #pragma unroll
            for (int r = 0; r < 4; ++r) {
                int c = 32 * wave + 16 * cti + 4 * g + r;
                size_t idx = ((size_t)b * CH + c) * NPOS + m0 + 16 * mt + lm;
                out[idx] = gmv * (acc[cti][mt][r] * linv[mt]) + x[idx];
            }
#undef BODY
#undef PVt
#undef QKW
#undef LOADV
#undef LOADK
}

extern "C" void kernel_launch(void* const* d_in, const int* in_sizes, int n_in,
                              void* d_out, int out_size, void* d_ws, size_t ws_size,
                              hipStream_t stream) {
    const float* x  = (const float*)d_in[0];
    const float* Wq = (const float*)d_in[1];
    const float* bq = (const float*)d_in[2];
    const float* Wk = (const float*)d_in[3];
    const float* bk = (const float*)d_in[4];
    const float* Wv = (const float*)d_in[5];
    const float* bv = (const float*)d_in[6];
    const float* gm = (const float*)d_in[7];
    float* out = (float*)d_out;

    __hip_bfloat16* qbuf = (__hip_bfloat16*)d_ws;
    __hip_bfloat16* kbuf = qbuf + (size_t)BATCH * NPOS * DQK;      // +1MB
    __hip_bfloat16* vbuf = kbuf + (size_t)BATCH * NPOS * DQK;      // +1MB
    __hip_bfloat16* wbf  = vbuf + (size_t)BATCH * CH * NPOS;       // +8MB
    float* bcat = (float*)(wbf + 320 * 256);                       // +160KB

    conv_w<<<dim3(320), 256, 0, stream>>>(Wq, bq, Wk, bk, Wv, bv, wbf, bcat);
    qkv_proj_mfma<<<dim3(NPOS / 32, BATCH), 256, 0, stream>>>(
        x, wbf, bcat, qbuf, kbuf, vbuf);
    flash_pam_kernel<<<dim3(NPOS / 64 * BATCH), 512, 0, stream>>>(
        qbuf, kbuf, vbuf, x, gm, out);
}